// Round 2
// baseline (54.705 us; speedup 1.0000x reference)
//
#include <hip/hip_runtime.h>

// PBC nonlinear compensation (real part of output only — harness stores
// the complex64 reference cast to float32, i.e. Re(O), [8, 16284, 2]):
//
// O[b,k,i] = E[b,k,i] + sum_{m,n} G[b,k;m,n] * C[m,n] * E[b,k-m,i]
//   G      = sum_j E[b,k-n,j] * conj(E[b,k-m-n,j])   (mode-summed, shared by i)
//
// Term set: |m|<=25, |n|<=25, |m*n|<=25 -> per m, n in [-lim, lim],
// lim = (m==0) ? 25 : 25/|m| (contiguous), T = 449, m-major t-order matches
// the Python (m outer, n inner) order of C[0][t]. Output k in [L, S-L) keeps
// all accesses in-range (no wraparound).

#define S_LEN   16384
#define SOUT    16284          // S - 2*L
#define BLK     256
#define HALO    50
#define NE      (BLK + 2*HALO) // 356 staged samples per block
#define T_CNT   449

__global__ __launch_bounds__(BLK) void pbc_kernel(
    const float* __restrict__ Er, const float* __restrict__ Ei,
    const float* __restrict__ Cr, const float* __restrict__ Ci,
    float* __restrict__ out)
{
    __shared__ float4 sE[NE];      // [k_local] = (e0.re, e0.im, e1.re, e1.im)
    __shared__ float2 sC[T_CNT];   // (cr, ci) per term

    const int b   = blockIdx.y;
    const int k0  = blockIdx.x * BLK;   // output-index origin of this block
    const int tid = threadIdx.x;

    // ---- stage E tile: global sample index kg = k0 + kl, kl in [0, NE) ----
    const float* erb = Er + (size_t)b * (S_LEN * 2);
    const float* eib = Ei + (size_t)b * (S_LEN * 2);
    for (int kl = tid; kl < NE; kl += BLK) {
        int kg = k0 + kl;
        float2 re = make_float2(0.f, 0.f), im = make_float2(0.f, 0.f);
        if (kg < S_LEN) {
            re = *reinterpret_cast<const float2*>(erb + 2 * kg); // modes 0,1
            im = *reinterpret_cast<const float2*>(eib + 2 * kg);
        }
        sE[kl] = make_float4(re.x, im.x, re.y, im.y);
    }
    // ---- stage C (row 0 of [4,T]) ----
    for (int t = tid; t < T_CNT; t += BLK)
        sC[t] = make_float2(Cr[t], Ci[t]);
    __syncthreads();

    // this thread's output sample: kout = k0 + tid (global k = kout + L).
    // sE[base - d] holds E[k - d] with base = tid + HALO.
    const int base = tid + HALO;

    float acc0r = 0.f, acc1r = 0.f;

    int t = 0;
    for (int m = -25; m <= 25; ++m) {
        const int am  = (m < 0) ? -m : m;
        const int lim = (m == 0) ? 25 : (25 / am);

        float smr = 0.f, smi = 0.f;   // sum_n C[m,n] * G(k; m, n)
        const int ia0 = base + lim;       // a = E[k-n] at n=-lim, descending
        const int ib0 = base - m + lim;   // b = E[k-m-n] at n=-lim
        for (int j = 0; j <= 2 * lim; ++j, ++t) {
            float4 a  = sE[ia0 - j];
            float4 bb = sE[ib0 - j];
            // G = sum_modes a * conj(b)
            float gr = a.x * bb.x + a.y * bb.y + a.z * bb.z + a.w * bb.w;
            float gi = a.y * bb.x - a.x * bb.y + a.w * bb.z - a.z * bb.w;
            float2 c = sC[t];
            smr += c.x * gr - c.y * gi;
            smi += c.x * gi + c.y * gr;
        }
        float4 e = sE[base - m];
        acc0r += smr * e.x - smi * e.y;   // Re(sm * E_0[k-m])
        acc1r += smr * e.z - smi * e.w;   // Re(sm * E_1[k-m])
    }

    const int kout = k0 + tid;
    if (kout < SOUT) {
        float4 e = sE[base];
        float2 o;
        o.x = e.x + acc0r;   // Re(O_0)
        o.y = e.z + acc1r;   // Re(O_1)
        reinterpret_cast<float2*>(out)[(size_t)b * SOUT + kout] = o;
    }
}

extern "C" void kernel_launch(void* const* d_in, const int* in_sizes, int n_in,
                              void* d_out, int out_size, void* d_ws, size_t ws_size,
                              hipStream_t stream) {
    const float* Er = (const float*)d_in[0];
    const float* Ei = (const float*)d_in[1];
    const float* Cr = (const float*)d_in[2];   // [4, 449], row 0 used
    const float* Ci = (const float*)d_in[3];
    float* out = (float*)d_out;                // [8, 16284, 2] float32 (Re)

    dim3 grid((SOUT + BLK - 1) / BLK, 8);
    pbc_kernel<<<grid, BLK, 0, stream>>>(Er, Ei, Cr, Ci, out);
}

// Round 3
// 34.738 us; speedup vs baseline: 1.5748x; 1.5748x over previous
//
#include <hip/hip_runtime.h>

// PBC nonlinear compensation, D-factorized:
//   O[b,k,i] = E[b,k,i] + sum_m sm(k;m) * E[b,k-m,i]        (Re part stored)
//   sm(k;m)  = sum_n C[m,n] * D_m[k-n]                      (1-D convolution)
//   D_m[x]   = sum_j E_j[x] * conj(E_j[x-m])                (shared across k!)
//   D_{-m}[x] = conj(D_m[x+m])  -> only m >= 0 tiles are computed.
//
// Term set: |m|<=25, |n|<=25, |m*n|<=25 -> per m, n in [-lim, lim],
// lim = (m==0) ? 25 : 25/|m|, T = 449, t-order = (m outer -25..25, n inner).

#define S_LEN   16384
#define SOUT    16284          // S - 2*L
#define BLK     256
#define HALO    50
#define NE      (BLK + 2*HALO) // 356 staged E samples per block
#define ND      307            // D tile: x in [k0+25, k0+331]
#define T_CNT   449

// lim(m) for m = 0..25
__device__ const int LIMS[26] = {25,25,12,8,6,5,4,3,3,2,2,2,2,
                                 1,1,1,1,1,1,1,1,1,1,1,1,1};
// t_start(m) for m = -25..25 (index m+25): cumulative term counts
__device__ const int TS[51] = {
      0,  3,  6,  9, 12, 15, 18, 21, 24, 27, 30, 33, 36,
     39, 44, 49, 54, 59, 66, 73, 82, 93,106,123,148,199,
    250,301,326,343,356,367,376,383,390,395,400,405,410,
    413,416,419,422,425,428,431,434,437,440,443,446};

__global__ __launch_bounds__(BLK) void pbc_kernel(
    const float* __restrict__ Er, const float* __restrict__ Ei,
    const float* __restrict__ Cr, const float* __restrict__ Ci,
    float* __restrict__ out)
{
    __shared__ float4 sE[NE];       // (e0.re, e0.im, e1.re, e1.im) per sample
    __shared__ float2 sC[T_CNT];    // (cr, ci) per term
    __shared__ float2 sD[2][ND];    // double-buffered D_m tile

    const int b   = blockIdx.y;
    const int k0  = blockIdx.x * BLK;
    const int tid = threadIdx.x;

    // ---- stage E tile: sE[kl] = E[k0 + kl] ----
    const float* erb = Er + (size_t)b * (S_LEN * 2);
    const float* eib = Ei + (size_t)b * (S_LEN * 2);
    for (int kl = tid; kl < NE; kl += BLK) {
        int kg = k0 + kl;
        float2 re = make_float2(0.f, 0.f), im = make_float2(0.f, 0.f);
        if (kg < S_LEN) {
            re = *reinterpret_cast<const float2*>(erb + 2 * kg);
            im = *reinterpret_cast<const float2*>(eib + 2 * kg);
        }
        sE[kl] = make_float4(re.x, im.x, re.y, im.y);
    }
    for (int t = tid; t < T_CNT; t += BLK)
        sC[t] = make_float2(Cr[t], Ci[t]);
    __syncthreads();

    // Output sample s = k0 + tid + 50 (global); E[s-d] = sE[tid+50-d].
    // D tile: sD[.][xl] = D_m[k0 + 25 + xl], E[x] = sE[xl + 25].
    float acc0 = 0.f, acc1 = 0.f;

    // ---- m = 0: D_0 real ----
    {
        for (int xl = tid; xl < ND; xl += BLK) {
            float4 a = sE[xl + 25];
            float d = a.x*a.x + a.y*a.y + a.z*a.z + a.w*a.w;
            sD[0][xl] = make_float2(d, 0.f);
        }
        __syncthreads();
        float smr = 0.f, smi = 0.f;
        const int x0 = tid + 50;           // xl for n = -25, descending
        for (int j = 0; j < 51; ++j) {
            float d  = sD[0][x0 - j].x;
            float2 c = sC[199 + j];
            smr += c.x * d;
            smi += c.y * d;
        }
        float4 e = sE[tid + 50];
        acc0 += smr * e.x - smi * e.y;
        acc1 += smr * e.z - smi * e.w;
    }

    // ---- m = 1..25: handle +m and -m from one D_m tile ----
    for (int m = 1; m <= 25; ++m) {
        float2* D = sD[m & 1];
        for (int xl = tid; xl < ND; xl += BLK) {
            float4 a = sE[xl + 25];
            float4 bb = sE[xl + 25 - m];
            float gr = a.x*bb.x + a.y*bb.y + a.z*bb.z + a.w*bb.w;
            float gi = a.y*bb.x - a.x*bb.y + a.w*bb.z - a.z*bb.w;
            D[xl] = make_float2(gr, gi);
        }
        __syncthreads();

        const int lim = LIMS[m];
        const int tp  = TS[25 + m];        // c row for +m
        const int tn  = TS[25 - m];        // c row for -m
        float smr_p = 0.f, smi_p = 0.f, smr_n = 0.f, smi_n = 0.f;
        const int xa = tid + 25 + lim;     // +m: D_m[s-n], n=-lim first
        const int xb = xa + m;             // -m: conj(D_m[s+m-n])
        const int ct = 2 * lim + 1;
        for (int j = 0; j < ct; ++j) {
            float2 dp = D[xa - j];
            float2 dn = D[xb - j];
            float2 cp = sC[tp + j];
            float2 cn = sC[tn + j];
            smr_p += cp.x*dp.x - cp.y*dp.y;
            smi_p += cp.x*dp.y + cp.y*dp.x;
            smr_n += cn.x*dn.x + cn.y*dn.y;      // conj(dn)
            smi_n += cn.y*dn.x - cn.x*dn.y;
        }
        float4 ep = sE[tid + 50 - m];      // E[s-m]
        float4 en = sE[tid + 50 + m];      // E[s+m]
        acc0 += smr_p*ep.x - smi_p*ep.y + smr_n*en.x - smi_n*en.y;
        acc1 += smr_p*ep.z - smi_p*ep.w + smr_n*en.z - smi_n*en.w;
    }

    const int kout = k0 + tid;
    if (kout < SOUT) {
        float4 e = sE[tid + 50];
        float2 o;
        o.x = e.x + acc0;
        o.y = e.z + acc1;
        reinterpret_cast<float2*>(out)[(size_t)b * SOUT + kout] = o;
    }
}

extern "C" void kernel_launch(void* const* d_in, const int* in_sizes, int n_in,
                              void* d_out, int out_size, void* d_ws, size_t ws_size,
                              hipStream_t stream) {
    const float* Er = (const float*)d_in[0];
    const float* Ei = (const float*)d_in[1];
    const float* Cr = (const float*)d_in[2];   // [4, 449], row 0 used
    const float* Ci = (const float*)d_in[3];
    float* out = (float*)d_out;                // [8, 16284, 2] float32 (Re)

    dim3 grid((SOUT + BLK - 1) / BLK, 8);
    pbc_kernel<<<grid, BLK, 0, stream>>>(Er, Ei, Cr, Ci, out);
}

// Round 4
// 27.544 us; speedup vs baseline: 1.9861x; 1.2612x over previous
//
#include <hip/hip_runtime.h>

// PBC nonlinear compensation, D-factorized, single-barrier schedule:
//   O[b,k,i] = E[b,k,i] + sum_m sm(k;m) * E[b,k-m,i]        (Re part stored)
//   sm(k;m)  = sum_n C[m,n] * D_m[k-n]                      (1-D convolution)
//   D_m[x]   = sum_j E_j[x] * conj(E_j[x-m]),  D_{-m}[x] = conj(D_m[x+m])
//
// All 26 D_m tiles (m = 0..25) are materialized in LDS in ONE phase
// (73 KB/block total; grid caps occupancy at 2 blocks/CU so LDS is free),
// then each wave runs its full 250-tap convolution with no further barriers.
//
// Term set: |m|<=25, |n|<=25, |m*n|<=25 -> per m, n in [-lim,lim],
// lim = (m==0) ? 25 : 25/|m|, T = 449, t-order = (m outer -25..25, n inner).

#define S_LEN   16384
#define SOUT    16284          // S - 2*L
#define BLK     256
#define NE      356            // staged E samples: [k0, k0+355]
#define ND      307            // D tile span: x in [k0+25, k0+331]
#define T_CNT   449
#define NM      26

__global__ __launch_bounds__(BLK) void pbc_kernel(
    const float* __restrict__ Er, const float* __restrict__ Ei,
    const float* __restrict__ Cr, const float* __restrict__ Ci,
    float* __restrict__ out)
{
    __shared__ float4 sE[NE];        // (e0.re, e0.im, e1.re, e1.im)
    __shared__ float2 sC[T_CNT];     // (cr, ci) per term
    __shared__ float2 sD[NM][ND];    // all D_m tiles

    const int b   = blockIdx.y;
    const int k0  = blockIdx.x * BLK;
    const int tid = threadIdx.x;

    // ---- stage E tile: sE[kl] = E[k0 + kl] ----
    const float* erb = Er + (size_t)b * (S_LEN * 2);
    const float* eib = Ei + (size_t)b * (S_LEN * 2);
    for (int kl = tid; kl < NE; kl += BLK) {
        int kg = k0 + kl;
        float2 re = make_float2(0.f, 0.f), im = make_float2(0.f, 0.f);
        if (kg < S_LEN) {
            re = *reinterpret_cast<const float2*>(erb + 2 * kg);
            im = *reinterpret_cast<const float2*>(eib + 2 * kg);
        }
        sE[kl] = make_float4(re.x, im.x, re.y, im.y);
    }
    __syncthreads();

    // ---- stage C + compute ALL D_m tiles in one phase ----
    for (int t = tid; t < T_CNT; t += BLK)
        sC[t] = make_float2(Cr[t], Ci[t]);

    for (int idx = tid; idx < NM * ND; idx += BLK) {
        int m  = idx / ND;            // const divisor -> magic multiply
        int xl = idx - m * ND;
        float4 a  = sE[xl + 25];
        float4 bb = sE[xl + 25 - m];
        float gr = a.x*bb.x + a.y*bb.y + a.z*bb.z + a.w*bb.w;
        float gi = a.y*bb.x - a.x*bb.y + a.w*bb.z - a.z*bb.w;
        sD[m][xl] = make_float2(gr, gi);
    }
    __syncthreads();

    // Output sample s = k0 + tid + 50 (global); E[s-d] = sE[tid+50-d];
    // sD[m][xl] = D_m[k0 + 25 + xl].
    float acc0 = 0.f, acc1 = 0.f;

    // ---- m = 0 (D_0 real) ----
    {
        float smr = 0.f, smi = 0.f;
        const int x0 = tid + 50;
        #pragma unroll
        for (int j = 0; j < 51; ++j) {
            float d  = sD[0][x0 - j].x;
            float2 c = sC[199 + j];
            smr = fmaf(c.x, d, smr);
            smi = fmaf(c.y, d, smi);
        }
        float4 e = sE[tid + 50];
        acc0 += smr * e.x - smi * e.y;
        acc1 += smr * e.z - smi * e.w;
    }

    // ---- m = 1..25, both signs from one tile (compile-time tables) ----
    constexpr int LIMS[26] = {25,25,12,8,6,5,4,3,3,2,2,2,2,
                              1,1,1,1,1,1,1,1,1,1,1,1,1};
    constexpr int TS[51] = {
          0,  3,  6,  9, 12, 15, 18, 21, 24, 27, 30, 33, 36,
         39, 44, 49, 54, 59, 66, 73, 82, 93,106,123,148,199,
        250,301,326,343,356,367,376,383,390,395,400,405,410,
        413,416,419,422,425,428,431,434,437,440,443,446};

    #pragma unroll
    for (int m = 1; m <= 25; ++m) {
        const int lim = LIMS[m];
        const int tp  = TS[25 + m];
        const int tn  = TS[25 - m];
        float smr_p = 0.f, smi_p = 0.f, smr_n = 0.f, smi_n = 0.f;
        const int xa = tid + 25 + lim;     // +m: D_m[s-n], n = -lim first
        const int xb = xa + m;             // -m: conj(D_m[s+m-n])
        #pragma unroll
        for (int j = 0; j < 2 * lim + 1; ++j) {
            float2 dp = sD[m][xa - j];
            float2 dn = sD[m][xb - j];
            float2 cp = sC[tp + j];
            float2 cn = sC[tn + j];
            smr_p += cp.x*dp.x - cp.y*dp.y;
            smi_p += cp.x*dp.y + cp.y*dp.x;
            smr_n += cn.x*dn.x + cn.y*dn.y;      // conj(dn)
            smi_n += cn.y*dn.x - cn.x*dn.y;
        }
        float4 ep = sE[tid + 50 - m];      // E[s-m]
        float4 en = sE[tid + 50 + m];      // E[s+m]
        acc0 += smr_p*ep.x - smi_p*ep.y + smr_n*en.x - smi_n*en.y;
        acc1 += smr_p*ep.z - smi_p*ep.w + smr_n*en.z - smi_n*en.w;
    }

    const int kout = k0 + tid;
    if (kout < SOUT) {
        float4 e = sE[tid + 50];
        float2 o;
        o.x = e.x + acc0;
        o.y = e.z + acc1;
        reinterpret_cast<float2*>(out)[(size_t)b * SOUT + kout] = o;
    }
}

extern "C" void kernel_launch(void* const* d_in, const int* in_sizes, int n_in,
                              void* d_out, int out_size, void* d_ws, size_t ws_size,
                              hipStream_t stream) {
    const float* Er = (const float*)d_in[0];
    const float* Ei = (const float*)d_in[1];
    const float* Cr = (const float*)d_in[2];   // [4, 449], row 0 used
    const float* Ci = (const float*)d_in[3];
    float* out = (float*)d_out;                // [8, 16284, 2] float32 (Re)

    dim3 grid((SOUT + BLK - 1) / BLK, 8);
    pbc_kernel<<<grid, BLK, 0, stream>>>(Er, Ei, Cr, Ci, out);
}

// Round 5
// 25.691 us; speedup vs baseline: 2.1294x; 1.0721x over previous
//
#include <hip/hip_runtime.h>

// PBC nonlinear compensation, D-factorized, single-barrier + split-m:
//   O[b,k,i] = E[b,k,i] + sum_m sm(k;m) * E[b,k-m,i]        (Re part stored)
//   sm(k;m)  = sum_n C[m,n] * D_m[k-n]                      (1-D convolution)
//   D_m[x]   = sum_j E_j[x] * conj(E_j[x-m]),  D_{-m}[x] = conj(D_m[x+m])
//
// 512 threads/block over 256 outputs: tid<256 computes m=0..3 (~846 FMA),
// tid>=256 computes m=4..25 (~848 FMA); partials combine via LDS.
// All 26 D_m tiles in LDS at once (75 KB/block, 2 blocks/CU), one conv
// phase with zero barriers inside.

#define S_LEN   16384
#define SOUT    16284          // S - 2*L
#define BLK     512
#define NOUT    256            // outputs per block
#define NE      356            // staged E samples: [k0, k0+355]
#define ND      307            // D tile span: x in [k0+25, k0+331]
#define T_CNT   449
#define NM      26

__global__ __launch_bounds__(BLK, 4) void pbc_kernel(
    const float* __restrict__ Er, const float* __restrict__ Ei,
    const float* __restrict__ Cr, const float* __restrict__ Ci,
    float* __restrict__ out)
{
    __shared__ float4 sE[NE];        // (e0.re, e0.im, e1.re, e1.im)
    __shared__ float2 sC[T_CNT];     // (cr, ci) per term
    __shared__ float2 sD[NM][ND];    // all D_m tiles
    __shared__ float2 sAcc[NOUT];    // half-1 partial accumulators

    const int b   = blockIdx.y;
    const int k0  = blockIdx.x * NOUT;
    const int tid = threadIdx.x;

    // ---- stage E tile: sE[kl] = E[k0 + kl] ----
    const float* erb = Er + (size_t)b * (S_LEN * 2);
    const float* eib = Ei + (size_t)b * (S_LEN * 2);
    for (int kl = tid; kl < NE; kl += BLK) {
        int kg = k0 + kl;
        float2 re = make_float2(0.f, 0.f), im = make_float2(0.f, 0.f);
        if (kg < S_LEN) {
            re = *reinterpret_cast<const float2*>(erb + 2 * kg);
            im = *reinterpret_cast<const float2*>(eib + 2 * kg);
        }
        sE[kl] = make_float4(re.x, im.x, re.y, im.y);
    }
    __syncthreads();

    // ---- stage C + compute ALL D_m tiles in one phase ----
    for (int t = tid; t < T_CNT; t += BLK)
        sC[t] = make_float2(Cr[t], Ci[t]);

    for (int idx = tid; idx < NM * ND; idx += BLK) {
        int m  = idx / ND;            // const divisor -> magic multiply
        int xl = idx - m * ND;
        float4 a  = sE[xl + 25];
        float4 bb = sE[xl + 25 - m];
        float gr = a.x*bb.x + a.y*bb.y + a.z*bb.z + a.w*bb.w;
        float gi = a.y*bb.x - a.x*bb.y + a.w*bb.z - a.z*bb.w;
        sD[m][xl] = make_float2(gr, gi);
    }
    __syncthreads();

    // Output sample s = k0 + to + 50 (global); E[s-d] = sE[to+50-d];
    // sD[m][xl] = D_m[k0 + 25 + xl].
    const int to   = tid & (NOUT - 1);
    const int half = tid >> 8;          // 0: m<=3, 1: m>=4 (wave-uniform)

    constexpr int LIMS[26] = {25,25,12,8,6,5,4,3,3,2,2,2,2,
                              1,1,1,1,1,1,1,1,1,1,1,1,1};
    constexpr int TS[51] = {
          0,  3,  6,  9, 12, 15, 18, 21, 24, 27, 30, 33, 36,
         39, 44, 49, 54, 59, 66, 73, 82, 93,106,123,148,199,
        250,301,326,343,356,367,376,383,390,395,400,405,410,
        413,416,419,422,425,428,431,434,437,440,443,446};

    float acc0 = 0.f, acc1 = 0.f;

#define CONV_M(MV)                                                         \
    {                                                                      \
        constexpr int m   = (MV);                                          \
        constexpr int lim = LIMS[m];                                       \
        constexpr int tp  = TS[25 + m];                                    \
        constexpr int tn  = TS[25 - m];                                    \
        float smr_p = 0.f, smi_p = 0.f, smr_n = 0.f, smi_n = 0.f;          \
        const int xa = to + 25 + lim;                                      \
        const int xb = xa + m;                                             \
        _Pragma("unroll")                                                  \
        for (int j = 0; j < 2 * lim + 1; ++j) {                            \
            float2 dp = sD[m][xa - j];                                     \
            float2 dn = sD[m][xb - j];                                     \
            float2 cp = sC[tp + j];                                        \
            float2 cn = sC[tn + j];                                        \
            smr_p += cp.x*dp.x - cp.y*dp.y;                                \
            smi_p += cp.x*dp.y + cp.y*dp.x;                                \
            smr_n += cn.x*dn.x + cn.y*dn.y;      /* conj(dn) */            \
            smi_n += cn.y*dn.x - cn.x*dn.y;                                \
        }                                                                  \
        float4 ep = sE[to + 50 - m];      /* E[s-m] */                     \
        float4 en = sE[to + 50 + m];      /* E[s+m] */                     \
        acc0 += smr_p*ep.x - smi_p*ep.y + smr_n*en.x - smi_n*en.y;         \
        acc1 += smr_p*ep.z - smi_p*ep.w + smr_n*en.z - smi_n*en.w;         \
    }

    if (half == 0) {
        // ---- m = 0 (D_0 real) ----
        {
            float smr = 0.f, smi = 0.f;
            const int x0 = to + 50;
            #pragma unroll
            for (int j = 0; j < 51; ++j) {
                float d  = sD[0][x0 - j].x;
                float2 c = sC[199 + j];
                smr = fmaf(c.x, d, smr);
                smi = fmaf(c.y, d, smi);
            }
            float4 e = sE[to + 50];
            acc0 += smr * e.x - smi * e.y;
            acc1 += smr * e.z - smi * e.w;
        }
        CONV_M(1) CONV_M(2) CONV_M(3)
    } else {
        CONV_M(4)  CONV_M(5)  CONV_M(6)  CONV_M(7)  CONV_M(8)
        CONV_M(9)  CONV_M(10) CONV_M(11) CONV_M(12) CONV_M(13)
        CONV_M(14) CONV_M(15) CONV_M(16) CONV_M(17) CONV_M(18)
        CONV_M(19) CONV_M(20) CONV_M(21) CONV_M(22) CONV_M(23)
        CONV_M(24) CONV_M(25)
        sAcc[to] = make_float2(acc0, acc1);
    }
    __syncthreads();

    const int kout = k0 + to;
    if (half == 0 && kout < SOUT) {
        float2 p = sAcc[to];
        float4 e = sE[to + 50];
        float2 o;
        o.x = e.x + acc0 + p.x;
        o.y = e.z + acc1 + p.y;
        reinterpret_cast<float2*>(out)[(size_t)b * SOUT + kout] = o;
    }
#undef CONV_M
}

extern "C" void kernel_launch(void* const* d_in, const int* in_sizes, int n_in,
                              void* d_out, int out_size, void* d_ws, size_t ws_size,
                              hipStream_t stream) {
    const float* Er = (const float*)d_in[0];
    const float* Ei = (const float*)d_in[1];
    const float* Cr = (const float*)d_in[2];   // [4, 449], row 0 used
    const float* Ci = (const float*)d_in[3];
    float* out = (float*)d_out;                // [8, 16284, 2] float32 (Re)

    dim3 grid((SOUT + NOUT - 1) / NOUT, 8);
    pbc_kernel<<<grid, BLK, 0, stream>>>(Er, Ei, Cr, Ci, out);
}

// Round 6
// 25.685 us; speedup vs baseline: 2.1299x; 1.0002x over previous
//
#include <hip/hip_runtime.h>

// PBC nonlinear compensation, D-factorized, single-barrier + 4-way m-split:
//   O[b,k,i] = E[b,k,i] + sum_m sm(k;m) * E[b,k-m,i]        (Re part stored)
//   sm(k;m)  = sum_n C[m,n] * D_m[k-n]                      (1-D convolution)
//   D_m[x]   = sum_j E_j[x] * conj(E_j[x-m]),  D_{-m}[x] = conj(D_m[x+m])
//
// 1024 threads/block over 256 outputs; quarters own disjoint m-sets
// (balanced ~420 FMA each); partials combine via LDS. All 26 D_m tiles
// in LDS (77.4 KB/block -> 2 blocks/CU = 8 waves/SIMD, max occupancy).

#define S_LEN   16384
#define SOUT    16284          // S - 2*L
#define BLK     1024
#define NOUT    256            // outputs per block
#define NE      356            // staged E samples: [k0, k0+355]
#define ND      307            // D tile span: x in [k0+25, k0+331]
#define T_CNT   449
#define NM      26

__global__ __launch_bounds__(BLK, 8) void pbc_kernel(
    const float* __restrict__ Er, const float* __restrict__ Ei,
    const float* __restrict__ Cr, const float* __restrict__ Ci,
    float* __restrict__ out)
{
    __shared__ float4 sE[NE];        // (e0.re, e0.im, e1.re, e1.im)
    __shared__ float2 sC[T_CNT];     // (cr, ci) per term
    __shared__ float2 sD[NM][ND];    // all D_m tiles
    __shared__ float2 sAcc[3][NOUT]; // partials from quarters 1..3

    const int b   = blockIdx.y;
    const int k0  = blockIdx.x * NOUT;
    const int tid = threadIdx.x;

    // ---- stage E tile: sE[kl] = E[k0 + kl] ----
    const float* erb = Er + (size_t)b * (S_LEN * 2);
    const float* eib = Ei + (size_t)b * (S_LEN * 2);
    for (int kl = tid; kl < NE; kl += BLK) {
        int kg = k0 + kl;
        float2 re = make_float2(0.f, 0.f), im = make_float2(0.f, 0.f);
        if (kg < S_LEN) {
            re = *reinterpret_cast<const float2*>(erb + 2 * kg);
            im = *reinterpret_cast<const float2*>(eib + 2 * kg);
        }
        sE[kl] = make_float4(re.x, im.x, re.y, im.y);
    }
    __syncthreads();

    // ---- stage C + compute ALL D_m tiles in one phase ----
    for (int t = tid; t < T_CNT; t += BLK)
        sC[t] = make_float2(Cr[t], Ci[t]);

    for (int idx = tid; idx < NM * ND; idx += BLK) {
        int m  = idx / ND;            // const divisor -> magic multiply
        int xl = idx - m * ND;
        float4 a  = sE[xl + 25];
        float4 bb = sE[xl + 25 - m];
        float gr = a.x*bb.x + a.y*bb.y + a.z*bb.z + a.w*bb.w;
        float gi = a.y*bb.x - a.x*bb.y + a.w*bb.z - a.z*bb.w;
        sD[m][xl] = make_float2(gr, gi);
    }
    __syncthreads();

    // Output sample s = k0 + to + 50 (global); E[s-d] = sE[to+50-d];
    // sD[m][xl] = D_m[k0 + 25 + xl].
    const int to = tid & (NOUT - 1);
    const int q  = tid >> 8;            // quarter, wave-uniform

    constexpr int LIMS[26] = {25,25,12,8,6,5,4,3,3,2,2,2,2,
                              1,1,1,1,1,1,1,1,1,1,1,1,1};
    constexpr int TS[51] = {
          0,  3,  6,  9, 12, 15, 18, 21, 24, 27, 30, 33, 36,
         39, 44, 49, 54, 59, 66, 73, 82, 93,106,123,148,199,
        250,301,326,343,356,367,376,383,390,395,400,405,410,
        413,416,419,422,425,428,431,434,437,440,443,446};

    float acc0 = 0.f, acc1 = 0.f;

#define CONV_M(MV)                                                         \
    {                                                                      \
        constexpr int m   = (MV);                                          \
        constexpr int lim = LIMS[m];                                       \
        constexpr int tp  = TS[25 + m];                                    \
        constexpr int tn  = TS[25 - m];                                    \
        float smr_p = 0.f, smi_p = 0.f, smr_n = 0.f, smi_n = 0.f;          \
        const int xa = to + 25 + lim;                                      \
        const int xb = xa + m;                                             \
        _Pragma("unroll")                                                  \
        for (int j = 0; j < 2 * lim + 1; ++j) {                            \
            float2 dp = sD[m][xa - j];                                     \
            float2 dn = sD[m][xb - j];                                     \
            float2 cp = sC[tp + j];                                        \
            float2 cn = sC[tn + j];                                        \
            smr_p += cp.x*dp.x - cp.y*dp.y;                                \
            smi_p += cp.x*dp.y + cp.y*dp.x;                                \
            smr_n += cn.x*dn.x + cn.y*dn.y;      /* conj(dn) */            \
            smi_n += cn.y*dn.x - cn.x*dn.y;                                \
        }                                                                  \
        float4 ep = sE[to + 50 - m];      /* E[s-m] */                     \
        float4 en = sE[to + 50 + m];      /* E[s+m] */                     \
        acc0 += smr_p*ep.x - smi_p*ep.y + smr_n*en.x - smi_n*en.y;         \
        acc1 += smr_p*ep.z - smi_p*ep.w + smr_n*en.z - smi_n*en.w;         \
    }

    if (q == 0) {
        CONV_M(1) CONV_M(9)
    } else if (q == 1) {
        CONV_M(2) CONV_M(3) CONV_M(6)
        sAcc[0][to] = make_float2(acc0, acc1);
    } else if (q == 2) {
        // ---- m = 0 (D_0 real) ----
        {
            float smr = 0.f, smi = 0.f;
            const int x0 = to + 50;
            #pragma unroll
            for (int j = 0; j < 51; ++j) {
                float d  = sD[0][x0 - j].x;
                float2 c = sC[199 + j];
                smr = fmaf(c.x, d, smr);
                smi = fmaf(c.y, d, smi);
            }
            float4 e = sE[to + 50];
            acc0 += smr * e.x - smi * e.y;
            acc1 += smr * e.z - smi * e.w;
        }
        CONV_M(4) CONV_M(5) CONV_M(7) CONV_M(8)
        sAcc[1][to] = make_float2(acc0, acc1);
    } else {
        CONV_M(10) CONV_M(11) CONV_M(12) CONV_M(13) CONV_M(14)
        CONV_M(15) CONV_M(16) CONV_M(17) CONV_M(18) CONV_M(19)
        CONV_M(20) CONV_M(21) CONV_M(22) CONV_M(23) CONV_M(24)
        CONV_M(25)
        sAcc[2][to] = make_float2(acc0, acc1);
    }
    __syncthreads();

    const int kout = k0 + to;
    if (q == 0 && kout < SOUT) {
        float2 p1 = sAcc[0][to];
        float2 p2 = sAcc[1][to];
        float2 p3 = sAcc[2][to];
        float4 e  = sE[to + 50];
        float2 o;
        o.x = e.x + acc0 + p1.x + p2.x + p3.x;
        o.y = e.z + acc1 + p1.y + p2.y + p3.y;
        reinterpret_cast<float2*>(out)[(size_t)b * SOUT + kout] = o;
    }
#undef CONV_M
}

extern "C" void kernel_launch(void* const* d_in, const int* in_sizes, int n_in,
                              void* d_out, int out_size, void* d_ws, size_t ws_size,
                              hipStream_t stream) {
    const float* Er = (const float*)d_in[0];
    const float* Ei = (const float*)d_in[1];
    const float* Cr = (const float*)d_in[2];   // [4, 449], row 0 used
    const float* Ci = (const float*)d_in[3];
    float* out = (float*)d_out;                // [8, 16284, 2] float32 (Re)

    dim3 grid((SOUT + NOUT - 1) / NOUT, 8);
    pbc_kernel<<<grid, BLK, 0, stream>>>(Er, Ei, Cr, Ci, out);
}